// Round 1
// baseline (930.713 us; speedup 1.0000x reference)
//
#include <hip/hip_runtime.h>
#include <hip/hip_bf16.h>

typedef __bf16 bf16_t;
typedef bf16_t bf16x8 __attribute__((ext_vector_type(8)));
typedef float  f32x4  __attribute__((ext_vector_type(4)));

#define EPS 1e-5f

// ---------------------------------------------------------------------------
// Prep: BN fold + weight transpose/convert into MFMA B-fragment layout.
// B-frag for 16x16x32 mfma: frag[(kt*NT + nt)*64 + lane][j] = W[nt*16 + (lane&15)][kt*32 + (lane>>4)*8 + j]
// ---------------------------------------------------------------------------
__global__ __launch_bounds__(256) void prep_kernel(
    const float* __restrict__ op_w1, const float* __restrict__ op_w2,
    const float* __restrict__ nm_w1, const float* __restrict__ nm_w2,
    const float* __restrict__ op_g, const float* __restrict__ op_b,
    const float* __restrict__ op_m, const float* __restrict__ op_v,
    const float* __restrict__ nm_g, const float* __restrict__ nm_b,
    const float* __restrict__ nm_m, const float* __restrict__ nm_v,
    bf16_t* __restrict__ w1f, bf16_t* __restrict__ w2f,
    bf16_t* __restrict__ nw1f, bf16_t* __restrict__ nw2f,
    float* __restrict__ opsc, float* __restrict__ opsh,
    float* __restrict__ nmsc, float* __restrict__ nmsh)
{
    int t = blockIdx.x * 256 + threadIdx.x;
    if (t < 4096) {                       // op_w1: [256 out][128 in] -> [kt<4][nt<16][64][8]
        int g = t, lane = g & 63, nt = (g >> 6) & 15, kt = g >> 10;
        int n = nt * 16 + (lane & 15);
        int k0 = kt * 32 + (lane >> 4) * 8;
        const float* src = op_w1 + (size_t)n * 128 + k0;
        bf16x8 v;
        for (int j = 0; j < 8; ++j) v[j] = (bf16_t)src[j];
        *(bf16x8*)(w1f + (size_t)g * 8) = v;
    } else if (t < 12288) {               // op_w2: [256][256] -> [kt<8][nt<16][64][8]
        int g = t - 4096, lane = g & 63, nt = (g >> 6) & 15, kt = g >> 10;
        int n = nt * 16 + (lane & 15);
        int k0 = kt * 32 + (lane >> 4) * 8;
        const float* src = op_w2 + (size_t)n * 256 + k0;
        bf16x8 v;
        for (int j = 0; j < 8; ++j) v[j] = (bf16_t)src[j];
        *(bf16x8*)(w2f + (size_t)g * 8) = v;
    } else if (t < 14336) {               // nm_w1: [128][128] -> [kt<4][nt<8][64][8]
        int g = t - 12288, lane = g & 63, nt = (g >> 6) & 7, kt = g >> 9;
        int n = nt * 16 + (lane & 15);
        int k0 = kt * 32 + (lane >> 4) * 8;
        const float* src = nm_w1 + (size_t)n * 128 + k0;
        bf16x8 v;
        for (int j = 0; j < 8; ++j) v[j] = (bf16_t)src[j];
        *(bf16x8*)(nw1f + (size_t)g * 8) = v;
    } else if (t < 16384) {               // nm_w2: [128][128] -> [kt<4][nt<8][64][8]
        int g = t - 14336, lane = g & 63, nt = (g >> 6) & 7, kt = g >> 9;
        int n = nt * 16 + (lane & 15);
        int k0 = kt * 32 + (lane >> 4) * 8;
        const float* src = nm_w2 + (size_t)n * 128 + k0;
        bf16x8 v;
        for (int j = 0; j < 8; ++j) v[j] = (bf16_t)src[j];
        *(bf16x8*)(nw2f + (size_t)g * 8) = v;
    } else if (t < 16512) {               // op BN fold
        int c = t - 16384;
        float s = op_g[c] / sqrtf(op_v[c] + EPS);
        opsc[c] = s;
        opsh[c] = op_b[c] - op_m[c] * s;
    } else if (t < 16640) {               // nm BN fold
        int c = t - 16512;
        float s = nm_g[c] / sqrtf(nm_v[c] + EPS);
        nmsc[c] = s;
        nmsh[c] = nm_b[c] - nm_m[c] * s;
    }
}

// ---------------------------------------------------------------------------
// Kernel 1: fused BN + Linear(128->256) + ReLU + Linear(256->256) + atomic scatter
// 64 tokens / block, 4 waves, wave mt owns token rows [mt*16, mt*16+16).
// ---------------------------------------------------------------------------
__global__ __launch_bounds__(256) void mlp1_scatter(
    const float* __restrict__ x, const int* __restrict__ tix,
    const float* __restrict__ opsc, const float* __restrict__ opsh,
    const bf16_t* __restrict__ w1f, const bf16_t* __restrict__ w2f,
    const float* __restrict__ b1, const float* __restrict__ b2,
    float* __restrict__ nf, int T, int N)
{
    __shared__ __align__(16) bf16_t Ax[4 * 4 * 64 * 8];   // [mt][kt<4][lane][8]  16 KB
    __shared__ __align__(16) bf16_t Hf[4 * 8 * 64 * 8];   // [mt][kt<8][lane][8]  32 KB
    const int tid  = threadIdx.x;
    const int base = blockIdx.x * 64;

    // ---- stage X tile with BN folded, into A-fragment layout ----
    {
        const int rr = tid >> 4;      // 0..15
        const int kg = tid & 15;      // 8-col group
        const int c0 = kg * 8;
        float sc[8], sh[8];
        for (int j = 0; j < 8; ++j) { sc[j] = opsc[c0 + j]; sh[j] = opsh[c0 + j]; }
        for (int p = 0; p < 4; ++p) {
            int r   = p * 16 + rr;
            int tok = base + r;
            float f[8];
            if (tok < T) {
                const float4* xp = (const float4*)(x + (size_t)tok * 128 + c0);
                float4 u = xp[0], w = xp[1];
                f[0] = u.x; f[1] = u.y; f[2] = u.z; f[3] = u.w;
                f[4] = w.x; f[5] = w.y; f[6] = w.z; f[7] = w.w;
            } else {
                for (int j = 0; j < 8; ++j) f[j] = 0.f;
            }
            bf16x8 v;
            for (int j = 0; j < 8; ++j) v[j] = (bf16_t)(f[j] * sc[j] + sh[j]);
            int flat = (((r >> 4) * 4 + (kg >> 2)) * 64 + (kg & 3) * 16 + (r & 15)) * 8;
            *(bf16x8*)(Ax + flat) = v;
        }
    }
    __syncthreads();

    const int mt    = tid >> 6;
    const int l     = tid & 63;
    const int colL  = l & 15;
    const int quadw = l >> 4;

    // token indices for this lane's 4 rows (constant over nt loop)
    int i0[4], i1[4]; bool ok[4];
    for (int reg = 0; reg < 4; ++reg) {
        int tk = base + mt * 16 + quadw * 4 + reg;
        ok[reg] = tk < T;
        i0[reg] = ok[reg] ? tix[tk] : 0;
        i1[reg] = ok[reg] ? tix[T + tk] : 0;
    }

    // ---- GEMM1: H = relu(Xbn * W1^T + b1), write H as A-frags to LDS ----
    bf16x8 a1[4];
    for (int kt = 0; kt < 4; ++kt)
        a1[kt] = *(const bf16x8*)(Ax + ((mt * 4 + kt) * 64 + l) * 8);
    for (int nt = 0; nt < 16; ++nt) {
        f32x4 acc = {0.f, 0.f, 0.f, 0.f};
        for (int kt = 0; kt < 4; ++kt) {
            bf16x8 b = *(const bf16x8*)(w1f + (size_t)((kt * 16 + nt) * 64 + l) * 8);
            acc = __builtin_amdgcn_mfma_f32_16x16x32_bf16(a1[kt], b, acc, 0, 0, 0);
        }
        float bb = b1[nt * 16 + colL];
        int c   = nt * 16 + colL;
        int kt2 = c >> 5, q2 = (c >> 3) & 3, j2 = c & 7;
        int hbase = ((mt * 8 + kt2) * 64 + q2 * 16) * 8 + j2;
        for (int reg = 0; reg < 4; ++reg) {
            float h = acc[reg] + bb;
            h = h > 0.f ? h : 0.f;
            int m2 = quadw * 4 + reg;
            Hf[hbase + m2 * 8] = (bf16_t)h;
        }
    }

    // ---- GEMM2: Y = H * W2^T + b2, scatter-add into nf ----
    bf16x8 a2[8];
    for (int kt = 0; kt < 8; ++kt)
        a2[kt] = *(const bf16x8*)(Hf + ((mt * 8 + kt) * 64 + l) * 8);
    for (int nt = 0; nt < 16; ++nt) {
        f32x4 acc = {0.f, 0.f, 0.f, 0.f};
        for (int kt = 0; kt < 8; ++kt) {
            bf16x8 b = *(const bf16x8*)(w2f + (size_t)((kt * 16 + nt) * 64 + l) * 8);
            acc = __builtin_amdgcn_mfma_f32_16x16x32_bf16(a2[kt], b, acc, 0, 0, 0);
        }
        float bb = b2[nt * 16 + colL];
        int c = nt * 16 + colL;
        if (c < 128) {              // uniform per nt (nt<8)
            for (int reg = 0; reg < 4; ++reg)
                if (ok[reg]) unsafeAtomicAdd(nf + (size_t)i0[reg] * 128 + c, acc[reg] + bb);
        } else {
            for (int reg = 0; reg < 4; ++reg)
                if (ok[reg]) unsafeAtomicAdd(nf + (size_t)i1[reg] * 128 + (c - 128), acc[reg] + bb);
        }
    }
}

// ---------------------------------------------------------------------------
// Kernel 2: node MLP: BN + Linear(128->128) + ReLU + Linear(128->128) -> out
// ---------------------------------------------------------------------------
__global__ __launch_bounds__(256) void mlp2_out(
    const float* __restrict__ nf,
    const float* __restrict__ nmsc, const float* __restrict__ nmsh,
    const bf16_t* __restrict__ w1f, const bf16_t* __restrict__ w2f,
    const float* __restrict__ b1, const float* __restrict__ b2,
    float* __restrict__ out, int N)
{
    __shared__ __align__(16) bf16_t Ax[4 * 4 * 64 * 8];   // 16 KB
    __shared__ __align__(16) bf16_t Hf[4 * 4 * 64 * 8];   // 16 KB
    const int tid  = threadIdx.x;
    const int base = blockIdx.x * 64;

    {
        const int rr = tid >> 4;
        const int kg = tid & 15;
        const int c0 = kg * 8;
        float sc[8], sh[8];
        for (int j = 0; j < 8; ++j) { sc[j] = nmsc[c0 + j]; sh[j] = nmsh[c0 + j]; }
        for (int p = 0; p < 4; ++p) {
            int r   = p * 16 + rr;
            int row = base + r;
            float f[8];
            if (row < N) {
                const float4* xp = (const float4*)(nf + (size_t)row * 128 + c0);
                float4 u = xp[0], w = xp[1];
                f[0] = u.x; f[1] = u.y; f[2] = u.z; f[3] = u.w;
                f[4] = w.x; f[5] = w.y; f[6] = w.z; f[7] = w.w;
            } else {
                for (int j = 0; j < 8; ++j) f[j] = 0.f;
            }
            bf16x8 v;
            for (int j = 0; j < 8; ++j) v[j] = (bf16_t)(f[j] * sc[j] + sh[j]);
            int flat = (((r >> 4) * 4 + (kg >> 2)) * 64 + (kg & 3) * 16 + (r & 15)) * 8;
            *(bf16x8*)(Ax + flat) = v;
        }
    }
    __syncthreads();

    const int mt    = tid >> 6;
    const int l     = tid & 63;
    const int colL  = l & 15;
    const int quadw = l >> 4;

    bf16x8 a1[4];
    for (int kt = 0; kt < 4; ++kt)
        a1[kt] = *(const bf16x8*)(Ax + ((mt * 4 + kt) * 64 + l) * 8);
    for (int nt = 0; nt < 8; ++nt) {
        f32x4 acc = {0.f, 0.f, 0.f, 0.f};
        for (int kt = 0; kt < 4; ++kt) {
            bf16x8 b = *(const bf16x8*)(w1f + (size_t)((kt * 8 + nt) * 64 + l) * 8);
            acc = __builtin_amdgcn_mfma_f32_16x16x32_bf16(a1[kt], b, acc, 0, 0, 0);
        }
        float bb = b1[nt * 16 + colL];
        int c   = nt * 16 + colL;
        int kt2 = c >> 5, q2 = (c >> 3) & 3, j2 = c & 7;
        int hbase = ((mt * 4 + kt2) * 64 + q2 * 16) * 8 + j2;
        for (int reg = 0; reg < 4; ++reg) {
            float h = acc[reg] + bb;
            h = h > 0.f ? h : 0.f;
            int m2 = quadw * 4 + reg;
            Hf[hbase + m2 * 8] = (bf16_t)h;
        }
    }

    bf16x8 a2[4];
    for (int kt = 0; kt < 4; ++kt)
        a2[kt] = *(const bf16x8*)(Hf + ((mt * 4 + kt) * 64 + l) * 8);
    for (int nt = 0; nt < 8; ++nt) {
        f32x4 acc = {0.f, 0.f, 0.f, 0.f};
        for (int kt = 0; kt < 4; ++kt) {
            bf16x8 b = *(const bf16x8*)(w2f + (size_t)((kt * 8 + nt) * 64 + l) * 8);
            acc = __builtin_amdgcn_mfma_f32_16x16x32_bf16(a2[kt], b, acc, 0, 0, 0);
        }
        float bb = b2[nt * 16 + colL];
        int c = nt * 16 + colL;
        for (int reg = 0; reg < 4; ++reg) {
            int row = base + mt * 16 + quadw * 4 + reg;
            if (row < N) out[(size_t)row * 128 + c] = acc[reg] + bb;
        }
    }
}

// ---------------------------------------------------------------------------
extern "C" void kernel_launch(void* const* d_in, const int* in_sizes, int n_in,
                              void* d_out, int out_size, void* d_ws, size_t ws_size,
                              hipStream_t stream)
{
    const float* x     = (const float*)d_in[0];
    const int*   tix   = (const int*)d_in[3];
    const float* op_g  = (const float*)d_in[4];
    const float* op_b  = (const float*)d_in[5];
    const float* op_m  = (const float*)d_in[6];
    const float* op_v  = (const float*)d_in[7];
    const float* op_w1 = (const float*)d_in[8];
    const float* op_b1 = (const float*)d_in[9];
    const float* op_w2 = (const float*)d_in[10];
    const float* op_b2 = (const float*)d_in[11];
    const float* nm_g  = (const float*)d_in[12];
    const float* nm_b  = (const float*)d_in[13];
    const float* nm_m  = (const float*)d_in[14];
    const float* nm_v  = (const float*)d_in[15];
    const float* nm_w1 = (const float*)d_in[16];
    const float* nm_b1 = (const float*)d_in[17];
    const float* nm_w2 = (const float*)d_in[18];
    const float* nm_b2 = (const float*)d_in[19];

    const int T = in_sizes[0] / 128;
    const int N = in_sizes[2];

    char* w = (char*)d_ws;
    float* nf = (float*)w;
    size_t off = ((size_t)N * 128 * 4 + 255) & ~(size_t)255;
    bf16_t* w1f  = (bf16_t*)(w + off); off += (size_t)4096 * 8 * 2;
    bf16_t* w2f  = (bf16_t*)(w + off); off += (size_t)8192 * 8 * 2;
    bf16_t* nw1f = (bf16_t*)(w + off); off += (size_t)2048 * 8 * 2;
    bf16_t* nw2f = (bf16_t*)(w + off); off += (size_t)2048 * 8 * 2;
    float* opsc = (float*)(w + off); off += 512;
    float* opsh = (float*)(w + off); off += 512;
    float* nmsc = (float*)(w + off); off += 512;
    float* nmsh = (float*)(w + off); off += 512;

    hipMemsetAsync(nf, 0, (size_t)N * 128 * 4, stream);
    prep_kernel<<<65, 256, 0, stream>>>(op_w1, op_w2, nm_w1, nm_w2,
                                        op_g, op_b, op_m, op_v,
                                        nm_g, nm_b, nm_m, nm_v,
                                        w1f, w2f, nw1f, nw2f,
                                        opsc, opsh, nmsc, nmsh);
    mlp1_scatter<<<(T + 63) / 64, 256, 0, stream>>>(x, tix, opsc, opsh, w1f, w2f,
                                                    op_b1, op_b2, nf, T, N);
    mlp2_out<<<(N + 63) / 64, 256, 0, stream>>>(nf, nmsc, nmsh, nw1f, nw2f,
                                                nm_b1, nm_b2, (float*)d_out, N);
}